// Round 6
// baseline (144.029 us; speedup 1.0000x reference)
//
#include <hip/hip_runtime.h>
#include <hip/hip_bf16.h>

#define BB  8
#define CC  128
#define LXX 4096
#define LYY 1024
#define HH  4
#define DHH 32

typedef __attribute__((ext_vector_type(8))) short bf16x8;
typedef __attribute__((ext_vector_type(4))) float f32x4;

static __device__ __forceinline__ unsigned short f2bf(float f) {
    __hip_bfloat16 h = __float2bfloat16(f);
    return *reinterpret_cast<unsigned short*>(&h);
}

static __device__ __forceinline__ bf16x8 pack8(const float* f) {
    bf16x8 r;
#pragma unroll
    for (int i = 0; i < 8; ++i) {
        __hip_bfloat16 h = __float2bfloat16(f[i]);
        r[i] = *reinterpret_cast<short*>(&h);
    }
    return r;
}

// load 8 consecutive f32 weights and convert to one MFMA A-fragment
static __device__ __forceinline__ bf16x8 ldw8(const float* p) {
    float t[8];
    *(float4*)(t)     = *(const float4*)(p);
    *(float4*)(t + 4) = *(const float4*)(p + 4);
    return pack8(t);
}

// ================= merged MFMA projection (+fused conv for x) =================
// R6: (1) prepack kernel removed — each thread converts exactly the weight
// elements it feeds to MFMA into reg-resident bf16x8 fragments at block
// start (one-time, ~40 float4 L2-hot loads; removes a whole launch).
// (2) m-range split across blockIdx.y: half 0 = m 0..4, half 1 = m 5..7 +
// conv. 1280 blocks -> 5 waves/SIMD (was 2.5) and per-wave serial path
// halves. R5's LDS-transpose staging reverted: measured neutral (direct
// loads are already 64B-segment coalesced across each 16-lane group).
// Bit-identical math to R3 (same f2bf, same kk-order MFMA accumulation).
__global__ __launch_bounds__(256) void proj_all_kernel(
    const float* __restrict__ x, const float* __restrict__ y,
    const float* __restrict__ ipw, const float* __restrict__ ipb,
    const float* __restrict__ c1w, const float* __restrict__ c1b,
    const float* __restrict__ c2w, const float* __restrict__ c2b,
    unsigned short* __restrict__ Qb, unsigned short* __restrict__ Kb,
    float* __restrict__ localS, float qscale)
{
    int tid  = threadIdx.x;
    int wv   = tid >> 6;
    int lane = tid & 63;
    int n16  = lane & 15;
    int quad = lane >> 4;
    int mhalf = blockIdx.y;          // 0: m 0..4   1: m 5..7 + conv

    int blk = blockIdx.x;
    bool isX = (blk < 512);
    const float* src; const float* wrow; const float* bias;
    unsigned short* dst; int L, bi, l0; float scale;
    if (isX) {
        bi = blk >> 6; l0 = (blk & 63) * 64;
        src = x + (size_t)bi * CC * LXX; L = LXX;
        wrow = ipw; bias = ipb; dst = Qb; scale = qscale;
    } else {
        int b2 = blk - 512;
        bi = b2 >> 4; l0 = (b2 & 15) * 64;
        src = y + (size_t)bi * CC * LYY; L = LYY;
        wrow = ipw + CC * CC; bias = ipb + CC; dst = Kb; scale = 1.0f;
    }
    int lw = l0 + wv * 16;
    int myl = lw + n16;

    // ---- x/y staging: 64B-segment coalesced direct loads (R3 pattern) ----
    bf16x8 bfr[4];
#pragma unroll
    for (int kk = 0; kk < 4; ++kk) {
        float t[8];
        const float* p = src + (size_t)(kk * 32 + quad * 8) * L + myl;
#pragma unroll
        for (int j = 0; j < 8; ++j) t[j] = p[(size_t)j * L];
        bfr[kk] = pack8(t);
    }

    const f32x4 fzero = {0.f, 0.f, 0.f, 0.f};

    if (mhalf == 0) {
        // ---- m = 0..4: reg-resident weight fragments, then pure-MFMA loop ----
        bf16x8 aw[5][4];
#pragma unroll
        for (int mi = 0; mi < 5; ++mi)
#pragma unroll
            for (int kk = 0; kk < 4; ++kk)
                aw[mi][kk] = ldw8(wrow + (size_t)(mi * 16 + n16) * CC + kk * 32 + quad * 8);

#pragma unroll
        for (int mi = 0; mi < 5; ++mi) {
            int mc = mi * 16;
            f32x4 acc = fzero;
#pragma unroll
            for (int kk = 0; kk < 4; ++kk)
                acc = __builtin_amdgcn_mfma_f32_16x16x32_bf16(aw[mi][kk], bfr[kk], acc, 0, 0, 0);
            int h = mc >> 5, d0 = (mc & 31) + quad * 4;
            ushort4 u;
            float4 bq = *(const float4*)(bias + mc + quad * 4);
            u.x = f2bf((acc[0] + bq.x) * scale);
            u.y = f2bf((acc[1] + bq.y) * scale);
            u.z = f2bf((acc[2] + bq.z) * scale);
            u.w = f2bf((acc[3] + bq.w) * scale);
            *(ushort4*)(dst + (((size_t)(bi * HH + h) * L) + myl) * DHH + d0) = u;
        }
    } else {
        // ---- m = 5..7 (+ conv for x-blocks) ----
        bf16x8 aw[3][4];
#pragma unroll
        for (int mi = 0; mi < 3; ++mi)
#pragma unroll
            for (int kk = 0; kk < 4; ++kk)
                aw[mi][kk] = ldw8(wrow + (size_t)((mi + 5) * 16 + n16) * CC + kk * 32 + quad * 8);

#pragma unroll
        for (int mi = 0; mi < 3; ++mi) {
            int mc = (mi + 5) * 16;
            f32x4 acc = fzero;
#pragma unroll
            for (int kk = 0; kk < 4; ++kk)
                acc = __builtin_amdgcn_mfma_f32_16x16x32_bf16(aw[mi][kk], bfr[kk], acc, 0, 0, 0);
            int h = mc >> 5, d0 = (mc & 31) + quad * 4;
            ushort4 u;
            float4 bq = *(const float4*)(bias + mc + quad * 4);
            u.x = f2bf((acc[0] + bq.x) * scale);
            u.y = f2bf((acc[1] + bq.y) * scale);
            u.z = f2bf((acc[2] + bq.z) * scale);
            u.w = f2bf((acc[3] + bq.w) * scale);
            *(ushort4*)(dst + (((size_t)(bi * HH + h) * L) + myl) * DHH + d0) = u;
        }

        if (isX) {
            bf16x8 cw[2][4];
#pragma unroll
            for (int m2 = 0; m2 < 2; ++m2)
#pragma unroll
                for (int kk = 0; kk < 4; ++kk)
                    cw[m2][kk] = ldw8(c1w + (size_t)(m2 * 16 + n16) * CC + kk * 32 + quad * 8);

            float p = 0.f;
#pragma unroll
            for (int m2 = 0; m2 < 2; ++m2) {
                f32x4 hacc = fzero;
#pragma unroll
                for (int kk = 0; kk < 4; ++kk)
                    hacc = __builtin_amdgcn_mfma_f32_16x16x32_bf16(cw[m2][kk], bfr[kk], hacc, 0, 0, 0);
#pragma unroll
                for (int r = 0; r < 4; ++r) {
                    int o = m2 * 16 + quad * 4 + r;
                    p = fmaf(c2w[o], fmaxf(hacc[r] + c1b[o], 0.0f), p);
                }
            }
            p += __shfl_xor(p, 16, 64);
            p += __shfl_xor(p, 32, 64);
            if (quad == 0) {
                float s = p + c2b[0];
                localS[(size_t)bi * LXX + myl] = 1.0f / (1.0f + __expf(-s));
            }
        }
    }
}

// ================= fused attention (R8 structure — measured optimum) =================
// grid (LX/32, B), 256 thr = 4 waves; wave w owns key quarter [w*256, +256).
// MEASURED DEAD ENDS — do not retry: (R1) launch_bounds(512,8) forced
// 64-unified-reg cap -> 1.1 GB scratch spill, 272 us. (R2) key-split across
// kernels -> +15 us (duplicated prologue + launch gaps). (R4) 8 waves/128
// keys no-cap -> +35% VALU work (duplicated reduce trees/logs), occupancy
// pinned ~3 waves/SIMD by ~160 unified regs either way, 55.8 us.
// This 4-wave shape = 44.6 us, VALU 51% =~ the 23 us issue floor / 44.6.
__global__ __launch_bounds__(256, 4) void attn_fused_kernel(
    const unsigned short* __restrict__ Qh, const unsigned short* __restrict__ Kh,
    const float* __restrict__ localS,
    const float* __restrict__ gw, const float* __restrict__ gb,
    float* __restrict__ out)
{
    int tid = threadIdx.x;
    int w = tid >> 6;           // key quarter 0..3
    int lane = tid & 63;
    int n16 = lane & 15;
    int quad = lane >> 4;
    int bi = blockIdx.y;
    int q0 = blockIdx.x * 32;

    __shared__ float dlds[4][2][HH][16];   // [w][qt][h][row]
    __shared__ float mlds[4][2][16];       // [w][qt][row]

    bf16x8 afr[2][HH];
#pragma unroll
    for (int qt = 0; qt < 2; ++qt)
#pragma unroll
        for (int h = 0; h < HH; ++h)
            afr[qt][h] = *(const bf16x8*)(Qh +
                (((size_t)bi * HH + h) * LXX + q0 + qt * 16 + n16) * DHH + quad * 8);

    const unsigned short* Kbase = Kh + (((size_t)bi * HH) * LYY + w * 256 + n16) * DHH + quad * 8;

    const f32x4 fzero = {0.f, 0.f, 0.f, 0.f};

    // ---- phase 1: denominators over this wave's 256 keys ----
    f32x4 den[2][HH];
#pragma unroll
    for (int qt = 0; qt < 2; ++qt)
#pragma unroll
        for (int h = 0; h < HH; ++h) den[qt][h] = fzero;

#pragma unroll 2
    for (int t = 0; t < 16; ++t) {
        bf16x8 bfr[HH];
#pragma unroll
        for (int h = 0; h < HH; ++h)
            bfr[h] = *(const bf16x8*)(Kbase + ((size_t)h * LYY + t * 16) * DHH);
#pragma unroll
        for (int h = 0; h < HH; ++h) {
            f32x4 s0 = __builtin_amdgcn_mfma_f32_16x16x32_bf16(afr[0][h], bfr[h], fzero, 0, 0, 0);
            f32x4 s1 = __builtin_amdgcn_mfma_f32_16x16x32_bf16(afr[1][h], bfr[h], fzero, 0, 0, 0);
#pragma unroll
            for (int r = 0; r < 4; ++r) {
                den[0][h][r] += __builtin_amdgcn_exp2f(s0[r]);
                den[1][h][r] += __builtin_amdgcn_exp2f(s1[r]);
            }
        }
    }
#pragma unroll
    for (int off = 1; off < 16; off <<= 1)
#pragma unroll
        for (int qt = 0; qt < 2; ++qt)
#pragma unroll
            for (int h = 0; h < HH; ++h)
#pragma unroll
                for (int r = 0; r < 4; ++r)
                    den[qt][h][r] += __shfl_xor(den[qt][h][r], off, 64);
    if (n16 == 0) {
#pragma unroll
        for (int qt = 0; qt < 2; ++qt)
#pragma unroll
            for (int h = 0; h < HH; ++h)
#pragma unroll
                for (int r = 0; r < 4; ++r) dlds[w][qt][h][quad * 4 + r] = den[qt][h][r];
    }
    __syncthreads();

    // c = -log2(total den); broadcast LDS reads (same addr within quad -> no conflict)
    f32x4 cc[2][HH];
#pragma unroll
    for (int qt = 0; qt < 2; ++qt)
#pragma unroll
        for (int h = 0; h < HH; ++h)
#pragma unroll
            for (int r = 0; r < 4; ++r) {
                int row = quad * 4 + r;
                float d = dlds[0][qt][h][row] + dlds[1][qt][h][row] +
                          dlds[2][qt][h][row] + dlds[3][qt][h][row];
                cc[qt][h][r] = -__builtin_amdgcn_logf(d);
            }

    // ---- phase 2: f(k) = sum_h exp2(s + c_h); running max over keys ----
    f32x4 vm0 = fzero, vm1 = fzero;    // f(k) > 0, so 0 is a valid -inf
#pragma unroll 2
    for (int t = 0; t < 16; ++t) {
        bf16x8 bfr[HH];
#pragma unroll
        for (int h = 0; h < HH; ++h)
            bfr[h] = *(const bf16x8*)(Kbase + ((size_t)h * LYY + t * 16) * DHH);
        f32x4 f0 = fzero, f1 = fzero;
#pragma unroll
        for (int h = 0; h < HH; ++h) {
            f32x4 s0 = __builtin_amdgcn_mfma_f32_16x16x32_bf16(afr[0][h], bfr[h], cc[0][h], 0, 0, 0);
            f32x4 s1 = __builtin_amdgcn_mfma_f32_16x16x32_bf16(afr[1][h], bfr[h], cc[1][h], 0, 0, 0);
#pragma unroll
            for (int r = 0; r < 4; ++r) {
                f0[r] += __builtin_amdgcn_exp2f(s0[r]);
                f1[r] += __builtin_amdgcn_exp2f(s1[r]);
            }
        }
#pragma unroll
        for (int r = 0; r < 4; ++r) {
            vm0[r] = fmaxf(vm0[r], f0[r]);
            vm1[r] = fmaxf(vm1[r], f1[r]);
        }
    }
#pragma unroll
    for (int off = 1; off < 16; off <<= 1)
#pragma unroll
        for (int r = 0; r < 4; ++r) {
            vm0[r] = fmaxf(vm0[r], __shfl_xor(vm0[r], off, 64));
            vm1[r] = fmaxf(vm1[r], __shfl_xor(vm1[r], off, 64));
        }
    if (n16 == 0) {
#pragma unroll
        for (int r = 0; r < 4; ++r) {
            mlds[w][0][quad * 4 + r] = vm0[r];
            mlds[w][1][quad * 4 + r] = vm1[r];
        }
    }
    __syncthreads();
    if (tid < 32) {
        int qq = tid >> 4;
        int row = tid & 15;
        float m = fmaxf(fmaxf(mlds[0][qq][row], mlds[1][qq][row]),
                        fmaxf(mlds[2][qq][row], mlds[3][qq][row]));
        float cs = 0.25f * m;
        int orow = q0 + qq * 16 + row;
        float ls = localS[(size_t)bi * LXX + orow];
        float z = gw[0] * cs + gw[1] * ls + gb[0];
        float alpha = 1.0f / (1.0f + __expf(-z));
        out[(size_t)bi * LXX + orow] = alpha * cs + (1.0f - alpha) * ls;
    }
}

extern "C" void kernel_launch(void* const* d_in, const int* in_sizes, int n_in,
                              void* d_out, int out_size, void* d_ws, size_t ws_size,
                              hipStream_t stream) {
    const float* x   = (const float*)d_in[0];
    const float* y   = (const float*)d_in[1];
    const float* ipw = (const float*)d_in[2];
    const float* ipb = (const float*)d_in[3];
    const float* c1w = (const float*)d_in[4];
    const float* c1b = (const float*)d_in[5];
    const float* c2w = (const float*)d_in[6];
    const float* c2b = (const float*)d_in[7];
    const float* gw  = (const float*)d_in[8];
    const float* gb  = (const float*)d_in[9];
    float* out = (float*)d_out;

    float* localS = (float*)d_ws;                                // 32768 f32
    unsigned short* Qb = (unsigned short*)(localS + 32768);      // B*H*LX*DH bf16
    unsigned short* Kb = Qb + (size_t)BB * HH * LXX * DHH;       // B*H*LY*DH bf16

    // 1/sqrt(32) * log2(e): exp2-domain softmax, folded into Q only
    const float qscale = 0.17677669529663687f * 1.4426950408889634f;

    hipLaunchKernelGGL(proj_all_kernel, dim3(640, 2), dim3(256), 0, stream,
                       x, y, ipw, ipb, c1w, c1b, c2w, c2b, Qb, Kb, localS, qscale);
    hipLaunchKernelGGL(attn_fused_kernel, dim3(LXX / 32, BB), dim3(256), 0, stream,
                       Qb, Kb, localS, gw, gb, out);
}

// Round 7
// 139.547 us; speedup vs baseline: 1.0321x; 1.0321x over previous
//
#include <hip/hip_runtime.h>
#include <hip/hip_bf16.h>

#define BB  8
#define CC  128
#define LXX 4096
#define LYY 1024
#define HH  4
#define DHH 32

typedef __attribute__((ext_vector_type(8))) short bf16x8;
typedef __attribute__((ext_vector_type(4))) float f32x4;

static __device__ __forceinline__ unsigned short f2bf(float f) {
    __hip_bfloat16 h = __float2bfloat16(f);
    return *reinterpret_cast<unsigned short*>(&h);
}

static __device__ __forceinline__ bf16x8 pack8(const float* f) {
    bf16x8 r;
#pragma unroll
    for (int i = 0; i < 8; ++i) {
        __hip_bfloat16 h = __float2bfloat16(f[i]);
        r[i] = *reinterpret_cast<short*>(&h);
    }
    return r;
}

// load 8 consecutive f32 weights -> one MFMA A-fragment (bf16)
static __device__ __forceinline__ bf16x8 ldw8(const float* p) {
    float t[8];
    *(float4*)(t)     = *(const float4*)(p);
    *(float4*)(t + 4) = *(const float4*)(p + 4);
    return pack8(t);
}

// ================= K projection only =================
// grid 128 (bi 8 x l0 16), 256 thr. R3-proven body restricted to y.
// Weights converted reg-resident per m-step (L2-hot, no prepack launch).
__global__ __launch_bounds__(256) void kproj_kernel(
    const float* __restrict__ y, const float* __restrict__ ipw,
    const float* __restrict__ ipb, unsigned short* __restrict__ Kb)
{
    int tid  = threadIdx.x;
    int wv   = tid >> 6;
    int lane = tid & 63;
    int n16  = lane & 15;
    int quad = lane >> 4;

    int blk = blockIdx.x;
    int bi = blk >> 4, l0 = (blk & 15) * 64;
    const float* src  = y + (size_t)bi * CC * LYY;
    const float* wrow = ipw + CC * CC;           // Wk
    const float* bias = ipb + CC;
    int myl = l0 + wv * 16 + n16;

    bf16x8 bfr[4];
#pragma unroll
    for (int kk = 0; kk < 4; ++kk) {
        float t[8];
        const float* p = src + (size_t)(kk * 32 + quad * 8) * LYY + myl;
#pragma unroll
        for (int j = 0; j < 8; ++j) t[j] = p[(size_t)j * LYY];
        bfr[kk] = pack8(t);
    }

    const f32x4 fzero = {0.f, 0.f, 0.f, 0.f};
#pragma unroll 1
    for (int m = 0; m < 8; ++m) {
        int mc = m * 16;
        f32x4 acc = fzero;
#pragma unroll
        for (int kk = 0; kk < 4; ++kk)
            acc = __builtin_amdgcn_mfma_f32_16x16x32_bf16(
                ldw8(wrow + (size_t)(mc + n16) * CC + kk * 32 + quad * 8),
                bfr[kk], acc, 0, 0, 0);
        int h = mc >> 5, d0 = (mc & 31) + quad * 4;
        float4 bq = *(const float4*)(bias + mc + quad * 4);
        ushort4 u;
        u.x = f2bf(acc[0] + bq.x);
        u.y = f2bf(acc[1] + bq.y);
        u.z = f2bf(acc[2] + bq.z);
        u.w = f2bf(acc[3] + bq.w);
        *(ushort4*)(Kb + (((size_t)(bi * HH + h) * LYY) + myl) * DHH + d0) = u;
    }
}

// ================= fully fused: Q-proj + conv + attention + gate =================
// R7: Q never touches global memory. Each block computes its own 32 q-rows:
// per wave, stage x fragments (64 scalar loads, 64B-segment coalesced),
// waves split the 8 d-blocks (wave w: m=2w,2w+1), MFMA -> bias*qscale ->
// bf16 -> qlds[qt][l][d] (stride 136 to spread banks); conv rides on waves
// 2/3 reusing the same x fragments, localS kept in plds (no global buffer).
// After 1 syncthreads, afr = ds_read_b128 from qlds; attn phases unchanged
// (bit-identical rounding points vs the Qb path).
// MEASURED DEAD ENDS — do not retry: (R1) launch_bounds(512,8) cap ->
// 1.1 GB scratch spill; (R2) kernel-split softmax -> +15 us; (R4) 8-wave/
// 128-key -> +35% VALU (dup reduce trees); (R5) LDS-transposed x staging
// neutral; (R6) m-split proj -> dup staging, +8 us.
__global__ __launch_bounds__(256, 4) void attn_fused_kernel(
    const float* __restrict__ x, const unsigned short* __restrict__ Kh,
    const float* __restrict__ ipw, const float* __restrict__ ipb,
    const float* __restrict__ c1w, const float* __restrict__ c1b,
    const float* __restrict__ c2w, const float* __restrict__ c2b,
    const float* __restrict__ gw, const float* __restrict__ gb,
    float* __restrict__ out, float qscale)
{
    int tid = threadIdx.x;
    int w = tid >> 6;           // wave: key quarter AND Q-proj m-pair owner
    int lane = tid & 63;
    int n16 = lane & 15;
    int quad = lane >> 4;
    int bi = blockIdx.y;
    int q0 = blockIdx.x * 32;

    __shared__ unsigned short qlds[2][16][136];  // [qt][l][d], stride 136
    __shared__ float dlds[4][2][HH][16];
    __shared__ float mlds[4][2][16];
    __shared__ float plds[32];

    const float* xsrc = x + (size_t)bi * CC * LXX;
    const f32x4 fzero = {0.f, 0.f, 0.f, 0.f};

    // ---- Q-proj + conv prologue ----
#pragma unroll 1
    for (int qt = 0; qt < 2; ++qt) {
        // stage x fragments for l = q0 + qt*16 + n16 (B-operand)
        bf16x8 bq[4];
#pragma unroll
        for (int kk = 0; kk < 4; ++kk) {
            float t[8];
            const float* p = xsrc + (size_t)(kk * 32 + quad * 8) * LXX + q0 + qt * 16 + n16;
#pragma unroll
            for (int j = 0; j < 8; ++j) t[j] = p[(size_t)j * LXX];
            bq[kk] = pack8(t);
        }
        // wave w computes d-blocks m = 2w, 2w+1
#pragma unroll
        for (int mi = 0; mi < 2; ++mi) {
            int m = 2 * w + mi;
            f32x4 acc = fzero;
#pragma unroll
            for (int kk = 0; kk < 4; ++kk)
                acc = __builtin_amdgcn_mfma_f32_16x16x32_bf16(
                    ldw8(ipw + (size_t)(m * 16 + n16) * CC + kk * 32 + quad * 8),
                    bq[kk], acc, 0, 0, 0);
            float4 bv = *(const float4*)(ipb + m * 16 + quad * 4);
            ushort4 u;
            u.x = f2bf((acc[0] + bv.x) * qscale);
            u.y = f2bf((acc[1] + bv.y) * qscale);
            u.z = f2bf((acc[2] + bv.z) * qscale);
            u.w = f2bf((acc[3] + bv.w) * qscale);
            *(ushort4*)(&qlds[qt][n16][m * 16 + quad * 4]) = u;
        }
        // conv for this qt's 16 rows: wave 2 -> qt 0, wave 3 -> qt 1
        if (w == 2 + qt) {
            float p = 0.f;
#pragma unroll
            for (int m2 = 0; m2 < 2; ++m2) {
                f32x4 hacc = fzero;
#pragma unroll
                for (int kk = 0; kk < 4; ++kk)
                    hacc = __builtin_amdgcn_mfma_f32_16x16x32_bf16(
                        ldw8(c1w + (size_t)(m2 * 16 + n16) * CC + kk * 32 + quad * 8),
                        bq[kk], hacc, 0, 0, 0);
#pragma unroll
                for (int r = 0; r < 4; ++r) {
                    int o = m2 * 16 + quad * 4 + r;
                    p = fmaf(c2w[o], fmaxf(hacc[r] + c1b[o], 0.0f), p);
                }
            }
            p += __shfl_xor(p, 16, 64);
            p += __shfl_xor(p, 32, 64);
            if (quad == 0)
                plds[qt * 16 + n16] = 1.0f / (1.0f + __expf(-(p + c2b[0])));
        }
    }
    __syncthreads();

    // afr fragments from qlds: 8x ds_read_b128
    bf16x8 afr[2][HH];
#pragma unroll
    for (int qt = 0; qt < 2; ++qt)
#pragma unroll
        for (int h = 0; h < HH; ++h)
            afr[qt][h] = *(const bf16x8*)(&qlds[qt][n16][h * 32 + quad * 8]);

    const unsigned short* Kbase = Kh + (((size_t)bi * HH) * LYY + w * 256 + n16) * DHH + quad * 8;

    // ---- phase 1: denominators over this wave's 256 keys ----
    f32x4 den[2][HH];
#pragma unroll
    for (int qt = 0; qt < 2; ++qt)
#pragma unroll
        for (int h = 0; h < HH; ++h) den[qt][h] = fzero;

#pragma unroll 2
    for (int t = 0; t < 16; ++t) {
        bf16x8 bfr[HH];
#pragma unroll
        for (int h = 0; h < HH; ++h)
            bfr[h] = *(const bf16x8*)(Kbase + ((size_t)h * LYY + t * 16) * DHH);
#pragma unroll
        for (int h = 0; h < HH; ++h) {
            f32x4 s0 = __builtin_amdgcn_mfma_f32_16x16x32_bf16(afr[0][h], bfr[h], fzero, 0, 0, 0);
            f32x4 s1 = __builtin_amdgcn_mfma_f32_16x16x32_bf16(afr[1][h], bfr[h], fzero, 0, 0, 0);
#pragma unroll
            for (int r = 0; r < 4; ++r) {
                den[0][h][r] += __builtin_amdgcn_exp2f(s0[r]);
                den[1][h][r] += __builtin_amdgcn_exp2f(s1[r]);
            }
        }
    }
#pragma unroll
    for (int off = 1; off < 16; off <<= 1)
#pragma unroll
        for (int qt = 0; qt < 2; ++qt)
#pragma unroll
            for (int h = 0; h < HH; ++h)
#pragma unroll
                for (int r = 0; r < 4; ++r)
                    den[qt][h][r] += __shfl_xor(den[qt][h][r], off, 64);
    if (n16 == 0) {
#pragma unroll
        for (int qt = 0; qt < 2; ++qt)
#pragma unroll
            for (int h = 0; h < HH; ++h)
#pragma unroll
                for (int r = 0; r < 4; ++r) dlds[w][qt][h][quad * 4 + r] = den[qt][h][r];
    }
    __syncthreads();

    // c = -log2(total den)
    f32x4 cc[2][HH];
#pragma unroll
    for (int qt = 0; qt < 2; ++qt)
#pragma unroll
        for (int h = 0; h < HH; ++h)
#pragma unroll
            for (int r = 0; r < 4; ++r) {
                int row = quad * 4 + r;
                float d = dlds[0][qt][h][row] + dlds[1][qt][h][row] +
                          dlds[2][qt][h][row] + dlds[3][qt][h][row];
                cc[qt][h][r] = -__builtin_amdgcn_logf(d);
            }

    // ---- phase 2: f(k) = sum_h exp2(s + c_h); running key-max ----
    f32x4 vm0 = fzero, vm1 = fzero;
#pragma unroll 2
    for (int t = 0; t < 16; ++t) {
        bf16x8 bfr[HH];
#pragma unroll
        for (int h = 0; h < HH; ++h)
            bfr[h] = *(const bf16x8*)(Kbase + ((size_t)h * LYY + t * 16) * DHH);
        f32x4 f0 = fzero, f1 = fzero;
#pragma unroll
        for (int h = 0; h < HH; ++h) {
            f32x4 s0 = __builtin_amdgcn_mfma_f32_16x16x32_bf16(afr[0][h], bfr[h], cc[0][h], 0, 0, 0);
            f32x4 s1 = __builtin_amdgcn_mfma_f32_16x16x32_bf16(afr[1][h], bfr[h], cc[1][h], 0, 0, 0);
#pragma unroll
            for (int r = 0; r < 4; ++r) {
                f0[r] += __builtin_amdgcn_exp2f(s0[r]);
                f1[r] += __builtin_amdgcn_exp2f(s1[r]);
            }
        }
#pragma unroll
        for (int r = 0; r < 4; ++r) {
            vm0[r] = fmaxf(vm0[r], f0[r]);
            vm1[r] = fmaxf(vm1[r], f1[r]);
        }
    }
#pragma unroll
    for (int off = 1; off < 16; off <<= 1)
#pragma unroll
        for (int r = 0; r < 4; ++r) {
            vm0[r] = fmaxf(vm0[r], __shfl_xor(vm0[r], off, 64));
            vm1[r] = fmaxf(vm1[r], __shfl_xor(vm1[r], off, 64));
        }
    if (n16 == 0) {
#pragma unroll
        for (int r = 0; r < 4; ++r) {
            mlds[w][0][quad * 4 + r] = vm0[r];
            mlds[w][1][quad * 4 + r] = vm1[r];
        }
    }
    __syncthreads();
    if (tid < 32) {
        int qq = tid >> 4;
        int row = tid & 15;
        float m = fmaxf(fmaxf(mlds[0][qq][row], mlds[1][qq][row]),
                        fmaxf(mlds[2][qq][row], mlds[3][qq][row]));
        float cs = 0.25f * m;
        int orow = q0 + qq * 16 + row;
        float ls = plds[qq * 16 + row];
        float z = gw[0] * cs + gw[1] * ls + gb[0];
        float alpha = 1.0f / (1.0f + __expf(-z));
        out[(size_t)bi * LXX + orow] = alpha * cs + (1.0f - alpha) * ls;
    }
}

extern "C" void kernel_launch(void* const* d_in, const int* in_sizes, int n_in,
                              void* d_out, int out_size, void* d_ws, size_t ws_size,
                              hipStream_t stream) {
    const float* x   = (const float*)d_in[0];
    const float* y   = (const float*)d_in[1];
    const float* ipw = (const float*)d_in[2];
    const float* ipb = (const float*)d_in[3];
    const float* c1w = (const float*)d_in[4];
    const float* c1b = (const float*)d_in[5];
    const float* c2w = (const float*)d_in[6];
    const float* c2b = (const float*)d_in[7];
    const float* gw  = (const float*)d_in[8];
    const float* gb  = (const float*)d_in[9];
    float* out = (float*)d_out;

    unsigned short* Kb = (unsigned short*)d_ws;   // B*H*LY*DH bf16 = 2 MB

    // 1/sqrt(32) * log2(e): exp2-domain softmax, folded into Q only
    const float qscale = 0.17677669529663687f * 1.4426950408889634f;

    hipLaunchKernelGGL(kproj_kernel, dim3(128), dim3(256), 0, stream,
                       y, ipw, ipb, Kb);
    hipLaunchKernelGGL(attn_fused_kernel, dim3(LXX / 32, BB), dim3(256), 0, stream,
                       x, Kb, ipw, ipb, c1w, c1b, c2w, c2b, gw, gb, out, qscale);
}

// Round 8
// 130.720 us; speedup vs baseline: 1.1018x; 1.0675x over previous
//
#include <hip/hip_runtime.h>
#include <hip/hip_bf16.h>

#define BB  8
#define CC  128
#define LXX 4096
#define LYY 1024
#define HH  4
#define DHH 32

typedef __attribute__((ext_vector_type(8))) short bf16x8;
typedef __attribute__((ext_vector_type(4))) float f32x4;

static __device__ __forceinline__ unsigned short f2bf(float f) {
    __hip_bfloat16 h = __float2bfloat16(f);
    return *reinterpret_cast<unsigned short*>(&h);
}

static __device__ __forceinline__ bf16x8 pack8(const float* f) {
    bf16x8 r;
#pragma unroll
    for (int i = 0; i < 8; ++i) {
        __hip_bfloat16 h = __float2bfloat16(f[i]);
        r[i] = *reinterpret_cast<short*>(&h);
    }
    return r;
}

// load 8 consecutive f32 weights -> one MFMA A-fragment (bf16)
static __device__ __forceinline__ bf16x8 ldw8(const float* p) {
    float t[8];
    *(float4*)(t)     = *(const float4*)(p);
    *(float4*)(t + 4) = *(const float4*)(p + 4);
    return pack8(t);
}

// ================= K projection + weight prepack (one launch) =================
// blocks 0..255: K-proj, m-split (R7's 128-block version was 0.5 blocks/CU
// pure serial latency ~27 us; split m 0..3 / 4..7 -> 1 block/CU and block
// latency ~= staging + half m-loop).
// blocks 256..271: prepack wbf = bf16{Wq, Wk, conv1_w} (R3's proven lever,
// folded here to avoid a 3rd launch). attn reads wbf only (launch-ordered).
__global__ __launch_bounds__(256) void kproj_pre_kernel(
    const float* __restrict__ y, const float* __restrict__ ipw,
    const float* __restrict__ ipb, const float* __restrict__ c1w,
    unsigned short* __restrict__ Kb, unsigned short* __restrict__ wbf)
{
    int tid  = threadIdx.x;
    int blk  = blockIdx.x;

    if (blk >= 256) {
        // ---- prepack: 16 blocks x 2304 elems ----
        int base = (blk - 256) * 2304;
#pragma unroll
        for (int j = 0; j < 9; ++j) {
            int idx = base + j * 256 + tid;
            float v = (idx < 2 * CC * CC) ? ipw[idx] : c1w[idx - 2 * CC * CC];
            wbf[idx] = f2bf(v);
        }
        return;
    }

    int wv   = tid >> 6;
    int lane = tid & 63;
    int n16  = lane & 15;
    int quad = lane >> 4;

    int bi = blk >> 5;
    int rest = blk & 31;
    int l0 = (rest >> 1) * 64;
    int mh = rest & 1;                 // m-range half: 0..3 or 4..7
    const float* src  = y + (size_t)bi * CC * LYY;
    const float* wrow = ipw + CC * CC; // Wk (f32; converted inline — same launch)
    const float* bias = ipb + CC;
    int myl = l0 + wv * 16 + n16;

    bf16x8 bfr[4];
#pragma unroll
    for (int kk = 0; kk < 4; ++kk) {
        float t[8];
        const float* p = src + (size_t)(kk * 32 + quad * 8) * LYY + myl;
#pragma unroll
        for (int j = 0; j < 8; ++j) t[j] = p[(size_t)j * LYY];
        bfr[kk] = pack8(t);
    }

    const f32x4 fzero = {0.f, 0.f, 0.f, 0.f};
#pragma unroll 1
    for (int mi = 0; mi < 4; ++mi) {
        int m = mh * 4 + mi;
        int mc = m * 16;
        f32x4 acc = fzero;
#pragma unroll
        for (int kk = 0; kk < 4; ++kk)
            acc = __builtin_amdgcn_mfma_f32_16x16x32_bf16(
                ldw8(wrow + (size_t)(mc + n16) * CC + kk * 32 + quad * 8),
                bfr[kk], acc, 0, 0, 0);
        int h = mc >> 5, d0 = (mc & 31) + quad * 4;
        float4 bq = *(const float4*)(bias + mc + quad * 4);
        ushort4 u;
        u.x = f2bf(acc[0] + bq.x);
        u.y = f2bf(acc[1] + bq.y);
        u.z = f2bf(acc[2] + bq.z);
        u.w = f2bf(acc[3] + bq.w);
        *(ushort4*)(Kb + (((size_t)(bi * HH + h) * LYY) + myl) * DHH + d0) = u;
    }
}

// ================= fully fused: Q-proj + conv + attention + gate =================
// R8: R7 structure, but prologue weight fragments are direct bf16x8 loads
// from prepacked wbf (L2-hot 16B loads) instead of per-block f32->bf16
// conversion — removes ~550 VALU ops and shortens the pre-barrier dep chain
// (the R3 lesson, re-applied). Attn phases untouched (bit-identical).
// MEASURED DEAD ENDS — do not retry: (R1) launch_bounds(512,8) cap ->
// 1.1 GB scratch spill; (R2) kernel-split softmax -> +15 us; (R4) 8-wave/
// 128-key -> +35% VALU; (R5) LDS-transposed x staging neutral; (R6) m-split
// proj -> dup staging +8 us; (R7) per-block weight cvt in prologue -> +14 us
// on attn.
__global__ __launch_bounds__(256, 4) void attn_fused_kernel(
    const float* __restrict__ x, const unsigned short* __restrict__ Kh,
    const unsigned short* __restrict__ wbf, const float* __restrict__ ipb,
    const float* __restrict__ c1b,
    const float* __restrict__ c2w, const float* __restrict__ c2b,
    const float* __restrict__ gw, const float* __restrict__ gb,
    float* __restrict__ out, float qscale)
{
    int tid = threadIdx.x;
    int w = tid >> 6;           // wave: key quarter AND Q-proj m-pair owner
    int lane = tid & 63;
    int n16 = lane & 15;
    int quad = lane >> 4;
    int bi = blockIdx.y;
    int q0 = blockIdx.x * 32;

    __shared__ unsigned short qlds[2][16][136];  // [qt][l][d], stride 136
    __shared__ float dlds[4][2][HH][16];
    __shared__ float mlds[4][2][16];
    __shared__ float plds[32];

    const float* xsrc = x + (size_t)bi * CC * LXX;
    const unsigned short* wc1 = wbf + 2 * CC * CC;
    const f32x4 fzero = {0.f, 0.f, 0.f, 0.f};

    // ---- Q-proj + conv prologue ----
#pragma unroll 1
    for (int qt = 0; qt < 2; ++qt) {
        // stage x fragments for l = q0 + qt*16 + n16 (B-operand)
        bf16x8 bq[4];
#pragma unroll
        for (int kk = 0; kk < 4; ++kk) {
            float t[8];
            const float* p = xsrc + (size_t)(kk * 32 + quad * 8) * LXX + q0 + qt * 16 + n16;
#pragma unroll
            for (int j = 0; j < 8; ++j) t[j] = p[(size_t)j * LXX];
            bq[kk] = pack8(t);
        }
        // wave w computes d-blocks m = 2w, 2w+1 (weights: direct bf16 loads)
#pragma unroll
        for (int mi = 0; mi < 2; ++mi) {
            int m = 2 * w + mi;
            f32x4 acc = fzero;
#pragma unroll
            for (int kk = 0; kk < 4; ++kk)
                acc = __builtin_amdgcn_mfma_f32_16x16x32_bf16(
                    *(const bf16x8*)(wbf + (size_t)(m * 16 + n16) * CC + kk * 32 + quad * 8),
                    bq[kk], acc, 0, 0, 0);
            float4 bv = *(const float4*)(ipb + m * 16 + quad * 4);
            ushort4 u;
            u.x = f2bf((acc[0] + bv.x) * qscale);
            u.y = f2bf((acc[1] + bv.y) * qscale);
            u.z = f2bf((acc[2] + bv.z) * qscale);
            u.w = f2bf((acc[3] + bv.w) * qscale);
            *(ushort4*)(&qlds[qt][n16][m * 16 + quad * 4]) = u;
        }
        // conv for this qt's 16 rows: wave 2 -> qt 0, wave 3 -> qt 1
        if (w == 2 + qt) {
            float p = 0.f;
#pragma unroll
            for (int m2 = 0; m2 < 2; ++m2) {
                f32x4 hacc = fzero;
#pragma unroll
                for (int kk = 0; kk < 4; ++kk)
                    hacc = __builtin_amdgcn_mfma_f32_16x16x32_bf16(
                        *(const bf16x8*)(wc1 + (size_t)(m2 * 16 + n16) * CC + kk * 32 + quad * 8),
                        bq[kk], hacc, 0, 0, 0);
#pragma unroll
                for (int r = 0; r < 4; ++r) {
                    int o = m2 * 16 + quad * 4 + r;
                    p = fmaf(c2w[o], fmaxf(hacc[r] + c1b[o], 0.0f), p);
                }
            }
            p += __shfl_xor(p, 16, 64);
            p += __shfl_xor(p, 32, 64);
            if (quad == 0)
                plds[qt * 16 + n16] = 1.0f / (1.0f + __expf(-(p + c2b[0])));
        }
    }
    __syncthreads();

    // afr fragments from qlds: 8x ds_read_b128
    bf16x8 afr[2][HH];
#pragma unroll
    for (int qt = 0; qt < 2; ++qt)
#pragma unroll
        for (int h = 0; h < HH; ++h)
            afr[qt][h] = *(const bf16x8*)(&qlds[qt][n16][h * 32 + quad * 8]);

    const unsigned short* Kbase = Kh + (((size_t)bi * HH) * LYY + w * 256 + n16) * DHH + quad * 8;

    // ---- phase 1: denominators over this wave's 256 keys ----
    f32x4 den[2][HH];
#pragma unroll
    for (int qt = 0; qt < 2; ++qt)
#pragma unroll
        for (int h = 0; h < HH; ++h) den[qt][h] = fzero;

#pragma unroll 2
    for (int t = 0; t < 16; ++t) {
        bf16x8 bfr[HH];
#pragma unroll
        for (int h = 0; h < HH; ++h)
            bfr[h] = *(const bf16x8*)(Kbase + ((size_t)h * LYY + t * 16) * DHH);
#pragma unroll
        for (int h = 0; h < HH; ++h) {
            f32x4 s0 = __builtin_amdgcn_mfma_f32_16x16x32_bf16(afr[0][h], bfr[h], fzero, 0, 0, 0);
            f32x4 s1 = __builtin_amdgcn_mfma_f32_16x16x32_bf16(afr[1][h], bfr[h], fzero, 0, 0, 0);
#pragma unroll
            for (int r = 0; r < 4; ++r) {
                den[0][h][r] += __builtin_amdgcn_exp2f(s0[r]);
                den[1][h][r] += __builtin_amdgcn_exp2f(s1[r]);
            }
        }
    }
#pragma unroll
    for (int off = 1; off < 16; off <<= 1)
#pragma unroll
        for (int qt = 0; qt < 2; ++qt)
#pragma unroll
            for (int h = 0; h < HH; ++h)
#pragma unroll
                for (int r = 0; r < 4; ++r)
                    den[qt][h][r] += __shfl_xor(den[qt][h][r], off, 64);
    if (n16 == 0) {
#pragma unroll
        for (int qt = 0; qt < 2; ++qt)
#pragma unroll
            for (int h = 0; h < HH; ++h)
#pragma unroll
                for (int r = 0; r < 4; ++r) dlds[w][qt][h][quad * 4 + r] = den[qt][h][r];
    }
    __syncthreads();

    // c = -log2(total den)
    f32x4 cc[2][HH];
#pragma unroll
    for (int qt = 0; qt < 2; ++qt)
#pragma unroll
        for (int h = 0; h < HH; ++h)
#pragma unroll
            for (int r = 0; r < 4; ++r) {
                int row = quad * 4 + r;
                float d = dlds[0][qt][h][row] + dlds[1][qt][h][row] +
                          dlds[2][qt][h][row] + dlds[3][qt][h][row];
                cc[qt][h][r] = -__builtin_amdgcn_logf(d);
            }

    // ---- phase 2: f(k) = sum_h exp2(s + c_h); running key-max ----
    f32x4 vm0 = fzero, vm1 = fzero;
#pragma unroll 2
    for (int t = 0; t < 16; ++t) {
        bf16x8 bfr[HH];
#pragma unroll
        for (int h = 0; h < HH; ++h)
            bfr[h] = *(const bf16x8*)(Kbase + ((size_t)h * LYY + t * 16) * DHH);
        f32x4 f0 = fzero, f1 = fzero;
#pragma unroll
        for (int h = 0; h < HH; ++h) {
            f32x4 s0 = __builtin_amdgcn_mfma_f32_16x16x32_bf16(afr[0][h], bfr[h], cc[0][h], 0, 0, 0);
            f32x4 s1 = __builtin_amdgcn_mfma_f32_16x16x32_bf16(afr[1][h], bfr[h], cc[1][h], 0, 0, 0);
#pragma unroll
            for (int r = 0; r < 4; ++r) {
                f0[r] += __builtin_amdgcn_exp2f(s0[r]);
                f1[r] += __builtin_amdgcn_exp2f(s1[r]);
            }
        }
#pragma unroll
        for (int r = 0; r < 4; ++r) {
            vm0[r] = fmaxf(vm0[r], f0[r]);
            vm1[r] = fmaxf(vm1[r], f1[r]);
        }
    }
#pragma unroll
    for (int off = 1; off < 16; off <<= 1)
#pragma unroll
        for (int r = 0; r < 4; ++r) {
            vm0[r] = fmaxf(vm0[r], __shfl_xor(vm0[r], off, 64));
            vm1[r] = fmaxf(vm1[r], __shfl_xor(vm1[r], off, 64));
        }
    if (n16 == 0) {
#pragma unroll
        for (int r = 0; r < 4; ++r) {
            mlds[w][0][quad * 4 + r] = vm0[r];
            mlds[w][1][quad * 4 + r] = vm1[r];
        }
    }
    __syncthreads();
    if (tid < 32) {
        int qq = tid >> 4;
        int row = tid & 15;
        float m = fmaxf(fmaxf(mlds[0][qq][row], mlds[1][qq][row]),
                        fmaxf(mlds[2][qq][row], mlds[3][qq][row]));
        float cs = 0.25f * m;
        int orow = q0 + qq * 16 + row;
        float ls = plds[qq * 16 + row];
        float z = gw[0] * cs + gw[1] * ls + gb[0];
        float alpha = 1.0f / (1.0f + __expf(-z));
        out[(size_t)bi * LXX + orow] = alpha * cs + (1.0f - alpha) * ls;
    }
}

extern "C" void kernel_launch(void* const* d_in, const int* in_sizes, int n_in,
                              void* d_out, int out_size, void* d_ws, size_t ws_size,
                              hipStream_t stream) {
    const float* x   = (const float*)d_in[0];
    const float* y   = (const float*)d_in[1];
    const float* ipw = (const float*)d_in[2];
    const float* ipb = (const float*)d_in[3];
    const float* c1w = (const float*)d_in[4];
    const float* c1b = (const float*)d_in[5];
    const float* c2w = (const float*)d_in[6];
    const float* c2b = (const float*)d_in[7];
    const float* gw  = (const float*)d_in[8];
    const float* gb  = (const float*)d_in[9];
    float* out = (float*)d_out;

    unsigned short* Kb  = (unsigned short*)d_ws;                 // 2 MB bf16 K
    unsigned short* wbf = Kb + (size_t)BB * HH * LYY * DHH;      // 36864 bf16 weights

    // 1/sqrt(32) * log2(e): exp2-domain softmax, folded into Q only
    const float qscale = 0.17677669529663687f * 1.4426950408889634f;

    hipLaunchKernelGGL(kproj_pre_kernel, dim3(272), dim3(256), 0, stream,
                       y, ipw, ipb, c1w, Kb, wbf);
    hipLaunchKernelGGL(attn_fused_kernel, dim3(LXX / 32, BB), dim3(256), 0, stream,
                       x, Kb, wbf, ipb, c1b, c2w, c2b, gw, gb, out, qscale);
}